// Round 13
// baseline (240.697 us; speedup 1.0000x reference)
//
#include <hip/hip_runtime.h>
#include <hip/hip_bf16.h>
#include <cstdint>
#include <cstddef>

typedef __bf16 bf16;
typedef __bf16 bf16x2 __attribute__((ext_vector_type(2)));
typedef __bf16 bf16x4 __attribute__((ext_vector_type(4)));
typedef __bf16 bf16x8 __attribute__((ext_vector_type(8)));
typedef float  f32x4  __attribute__((ext_vector_type(4)));
typedef int    i32x4  __attribute__((ext_vector_type(4)));

#define DEVINL __device__ __forceinline__

constexpr int   Bc  = 2, Sc = 2048, Hc = 1024, NHc = 16, HDc = 64;
constexpr int   Tc  = Bc * Sc;                 // 4096 tokens
constexpr float L2E = 1.44269504088896340736f;
constexpr float NEG_BIG = -1.0e30f;

typedef __attribute__((address_space(1))) void AS1void;
typedef __attribute__((address_space(3))) void AS3void;

DEVINL void load_lds16(const bf16* g, bf16* l) {
  __builtin_amdgcn_global_load_lds((AS1void*)g, (AS3void*)l, 16, 0, 0);
}

DEVINL int packbf(float a, float b) {
  union { bf16x2 h; int i; } u;
  u.h[0] = (bf16)a; u.h[1] = (bf16)b;
  return u.i;
}

// XOR-swizzle: slot s of row r holds global chunk (s ^ (r & (R-1))) [R9: 41x conflict cut]
// XCD model [R11-validated]: XCD = flat_block_id % 8; same-CU blocks share bh
// and have y ≡ y0 (mod 8).

// ---------------------------------------------------------------------------
// Fused fp32->bf16 conversion of all inputs + bias pack, ONE dispatch.
// ---------------------------------------------------------------------------
__global__ __launch_bounds__(256)
void convert_all(const float* __restrict__ hs, const float* __restrict__ Wqkv,
                 const float* __restrict__ Wqa, const float* __restrict__ Wka,
                 const float* __restrict__ Wd, const float* __restrict__ bqa,
                 const float* __restrict__ bka,
                 bf16* __restrict__ hsb, bf16* __restrict__ wqkvb,
                 bf16* __restrict__ wqakab, bf16* __restrict__ wdb,
                 float* __restrict__ bqaka) {
  const int blk = blockIdx.x;
  if (blk >= 5120) {  // bias pack: 2048 floats
    const int i = threadIdx.x * 8;
    const float* src = (i < 1024) ? (bqa + i) : (bka + i - 1024);
    *(f32x4*)(bqaka + i)     = *(const f32x4*)src;
    *(f32x4*)(bqaka + i + 4) = *(const f32x4*)(src + 4);
    return;
  }
  const float* src; bf16* dst; int base;
  if      (blk < 2048) { src = hs;   dst = hsb;                    base = blk; }
  else if (blk < 3584) { src = Wqkv; dst = wqkvb;                  base = blk - 2048; }
  else if (blk < 4096) { src = Wqa;  dst = wqakab;                 base = blk - 3584; }
  else if (blk < 4608) { src = Wka;  dst = wqakab + 1024 * 1024;   base = blk - 4096; }
  else                 { src = Wd;   dst = wdb;                    base = blk - 4608; }
  const int i = (base * 256 + threadIdx.x) * 8;
  f32x4 a = *(const f32x4*)(src + i);
  f32x4 b = *(const f32x4*)(src + i + 4);
  bf16x8 v;
#pragma unroll
  for (int j = 0; j < 4; j++) { v[j] = (bf16)a[j]; v[4 + j] = (bf16)b[j]; }
  *(bf16x8*)(dst + i) = v;
}

// ---------------------------------------------------------------------------
// gemm128: C[M][N] = A[M][K] @ Bw[N][K]^T + bias[N]; 128x128 tile, BK=64,
// XOR-swizzled LDS. min 3 waves/EU.
// ---------------------------------------------------------------------------
template <typename CT>
__global__ __launch_bounds__(256, 3)
void gemm128(const bf16* __restrict__ A, const bf16* __restrict__ Bw,
             const float* __restrict__ bias, CT* __restrict__ C,
             int M, int N, int K) {
  __shared__ __attribute__((aligned(16))) bf16 As[128 * 64];
  __shared__ __attribute__((aligned(16))) bf16 Bs[128 * 64];

  const int tid = threadIdx.x, wv = tid >> 6, lane = tid & 63;
  const int m0 = blockIdx.y * 128, n0 = blockIdx.x * 128;
  const int col = lane & 15, quad = lane >> 4;
  const int wrow = (wv >> 1) * 64, wcol = (wv & 1) * 64;

  f32x4 acc[4][4];
#pragma unroll
  for (int i = 0; i < 4; i++)
#pragma unroll
    for (int j = 0; j < 4; j++) acc[i][j] = f32x4{0.f, 0.f, 0.f, 0.f};

  const int srow = tid >> 3;
  const int scol = (((tid & 7) ^ (srow & 7)) << 3);
  const bf16* Ag = A  + (size_t)(m0 + srow) * K + scol;
  const bf16* Bg = Bw + (size_t)(n0 + srow) * K + scol;
  const int cs = col & 7;

  for (int k0 = 0; k0 < K; k0 += 64) {
#pragma unroll
    for (int c = 0; c < 4; c++) {
      load_lds16(Ag + (size_t)(c * 32) * K + k0, As + c * 2048 + tid * 8);
      load_lds16(Bg + (size_t)(c * 32) * K + k0, Bs + c * 2048 + tid * 8);
    }
    __syncthreads();
#pragma unroll
    for (int kk = 0; kk < 64; kk += 32) {
      const int so = ((((kk >> 3) + quad) ^ cs) << 3);
      bf16x8 af[4], bfr[4];
#pragma unroll
      for (int i = 0; i < 4; i++)
        af[i] = *(const bf16x8*)(As + (wrow + i * 16 + col) * 64 + so);
#pragma unroll
      for (int j = 0; j < 4; j++)
        bfr[j] = *(const bf16x8*)(Bs + (wcol + j * 16 + col) * 64 + so);
#pragma unroll
      for (int i = 0; i < 4; i++)
#pragma unroll
        for (int j = 0; j < 4; j++)
          acc[i][j] = __builtin_amdgcn_mfma_f32_16x16x32_bf16(af[i], bfr[j], acc[i][j], 0, 0, 0);
    }
    __syncthreads();
  }

#pragma unroll
  for (int j = 0; j < 4; j++) {
    const int c = n0 + wcol + j * 16 + col;
    const float bv = bias[c];
#pragma unroll
    for (int i = 0; i < 4; i++)
#pragma unroll
      for (int r = 0; r < 4; r++) {
        const int rr = m0 + wrow + i * 16 + quad * 4 + r;
        C[(size_t)rr * N + c] = (CT)(acc[i][j][r] + bv);
      }
  }
}

// ---------------------------------------------------------------------------
// gemm6464: 64x64 tile; 1024 blocks for the final projection (4/CU).
// ---------------------------------------------------------------------------
template <typename CT>
__global__ __launch_bounds__(256, 4)
void gemm6464(const bf16* __restrict__ A, const bf16* __restrict__ Bw,
              const float* __restrict__ bias, CT* __restrict__ C,
              int M, int N, int K) {
  __shared__ __attribute__((aligned(16))) bf16 As[64 * 64];
  __shared__ __attribute__((aligned(16))) bf16 Bs[64 * 64];

  const int tid = threadIdx.x, wv = tid >> 6, lane = tid & 63;
  const int m0 = blockIdx.y * 64, n0 = blockIdx.x * 64;
  const int col = lane & 15, quad = lane >> 4;

  f32x4 acc[4];
#pragma unroll
  for (int j = 0; j < 4; j++) acc[j] = f32x4{0.f, 0.f, 0.f, 0.f};

  const int srow = tid >> 3;
  const int scol = (((tid & 7) ^ (srow & 7)) << 3);
  const bf16* Ag = A  + (size_t)(m0 + srow) * K + scol;
  const bf16* Bg = Bw + (size_t)(n0 + srow) * K + scol;
  const int cs = col & 7;

  for (int k0 = 0; k0 < K; k0 += 64) {
#pragma unroll
    for (int c = 0; c < 2; c++) {
      load_lds16(Ag + (size_t)(c * 32) * K + k0, As + c * 2048 + tid * 8);
      load_lds16(Bg + (size_t)(c * 32) * K + k0, Bs + c * 2048 + tid * 8);
    }
    __syncthreads();
#pragma unroll
    for (int kk = 0; kk < 64; kk += 32) {
      const int so = ((((kk >> 3) + quad) ^ cs) << 3);
      bf16x8 af = *(const bf16x8*)(As + (wv * 16 + col) * 64 + so);
#pragma unroll
      for (int j = 0; j < 4; j++) {
        bf16x8 bfr = *(const bf16x8*)(Bs + (j * 16 + col) * 64 + so);
        acc[j] = __builtin_amdgcn_mfma_f32_16x16x32_bf16(af, bfr, acc[j], 0, 0, 0);
      }
    }
    __syncthreads();
  }

#pragma unroll
  for (int j = 0; j < 4; j++) {
    const int c = n0 + j * 16 + col;
    const float bv = bias[c];
#pragma unroll
    for (int r = 0; r < 4; r++) {
      const int rr = m0 + wv * 16 + quad * 4 + r;
      C[(size_t)rr * N + c] = (CT)(acc[j][r] + bv);
    }
  }
}

// ---------------------------------------------------------------------------
// Sliding-window (W=16) attention with FUSED RoPE and FUSED V-transpose.
// ---------------------------------------------------------------------------
__global__ __launch_bounds__(256)
void window_attn(const bf16* __restrict__ qkv, bf16* __restrict__ Ah,
                 bf16* __restrict__ VTg) {
  __shared__ __attribute__((aligned(16))) bf16 Kw[31 * 72];
  __shared__ __attribute__((aligned(16))) bf16 Vw[31 * 72];
  const int g  = blockIdx.x;
  const int st = g & 127;
  const int h  = (g >> 7) & 15;
  const int b  = g >> 11;
  const int s0 = st * 16;
  const int tid = threadIdx.x;

  if ((tid < 124) || (tid >= 128 && tid < 252)) {
    const bool isK = tid < 124;
    const int lt  = isK ? tid : tid - 128;
    const int r   = lt >> 2, off = (lt & 3) << 4;
    int sidx = s0 - 15 + r; if (sidx < 0) sidx = 0;
    const bf16* src = qkv + (size_t)(b * Sc + sidx) * 3072 + (isK ? 1024 : 2048) + h * 64 + off;
    bf16x8 v0 = *(const bf16x8*)src;
    bf16x8 v1 = *(const bf16x8*)(src + 8);
    if (isK && off == 0) {
#pragma unroll
      for (int j = 0; j < 8; j++) {
        const float invf = exp2f(-(float)j * 1.66096404744368128f);
        float sn, csn;
        sincosf((float)sidx * invf, &sn, &csn);
        const float x1 = (float)v0[j], x2 = (float)v1[j];
        v0[j] = (bf16)(x1 * csn - x2 * sn);
        v1[j] = (bf16)(x2 * csn + x1 * sn);
      }
    }
    bf16* dst = (isK ? Kw : Vw) + r * 72 + off;
    *(bf16x8*)dst       = v0;
    *(bf16x8*)(dst + 8) = v1;
  }
  __syncthreads();

  const int wv = tid >> 6, lane = tid & 63;
  const int subq = lane >> 4, lane16 = lane & 15;
  const int s = s0 + wv * 4 + subq;
  const int t = b * Sc + s;
  const int d0 = lane16 * 4;

  float qd[4];
  {
    bf16x4 qv = *(const bf16x4*)(qkv + (size_t)t * 3072 + h * 64 + d0);
#pragma unroll
    for (int j = 0; j < 4; j++) qd[j] = (float)qv[j];
  }
  float pd[4];
#pragma unroll
  for (int j = 0; j < 4; j++) pd[j] = __shfl_xor(qd[j], 2, 64);
  if (lane16 < 4) {
#pragma unroll
    for (int j = 0; j < 4; j++) {
      const int jabs = d0 + j;
      const float invf = exp2f(-(float)(jabs & 7) * 1.66096404744368128f);
      float sn, csn;
      sincosf((float)s * invf, &sn, &csn);
      qd[j] = (jabs < 8) ? (qd[j] * csn - pd[j] * sn) : (qd[j] * csn + pd[j] * sn);
    }
  }

  float sc[16];
#pragma unroll
  for (int w = 0; w < 16; w++) {
    const int idxp = s - 15 + w;
    const int row = idxp - s0 + 15;
    bf16x4 kv = *(const bf16x4*)(Kw + row * 72 + d0);
    float p = qd[0] * (float)kv[0] + qd[1] * (float)kv[1] +
              qd[2] * (float)kv[2] + qd[3] * (float)kv[3];
#pragma unroll
    for (int m = 1; m < 16; m <<= 1) p += __shfl_xor(p, m, 64);
    sc[w] = (idxp < 0) ? NEG_BIG : p * 0.125f;
  }
  float mx = sc[0];
#pragma unroll
  for (int w = 1; w < 16; w++) mx = fmaxf(mx, sc[w]);
  float sum = 0.f;
#pragma unroll
  for (int w = 0; w < 16; w++) { sc[w] = exp2f((sc[w] - mx) * L2E); sum += sc[w]; }
  const float inv = 1.0f / fmaxf(sum, 1e-30f);

  float acc[4] = {0.f, 0.f, 0.f, 0.f};
#pragma unroll
  for (int w = 0; w < 16; w++) {
    const int idxp = s - 15 + w;
    const int row = idxp - s0 + 15;
    bf16x4 vv = *(const bf16x4*)(Vw + row * 72 + d0);
#pragma unroll
    for (int j = 0; j < 4; j++) acc[j] += sc[w] * (float)vv[j];
  }
  bf16x4 ov;
#pragma unroll
  for (int j = 0; j < 4; j++) ov[j] = (bf16)(acc[j] * inv);
  *(bf16x4*)(Ah + (size_t)t * 1024 + h * 64 + d0) = ov;
  bf16* vt = VTg + (((size_t)(b * 16 + h)) * 64 + d0) * 2048 + s;
#pragma unroll
  for (int j = 0; j < 4; j++) vt[(size_t)j * 2048] = ov[j];
}

// ---------------------------------------------------------------------------
// Dense causal flash attention — S^T FORMULATION (transpose-free):
//   S^T = mfma(K, Q): lane holds (key = quad*4+r, q = col).
//   out^T = mfma(V^T, P^T): P^T B-frag gathered from the 4 lanes sharing col
//   via ds_bpermute (2 bperm + 1 select per dword) — NO P_lds.
// LDS = K_lds + VT_lds = 32 KB exactly -> 4 blocks/CU resident, so the
// R12 CU-balancing qt permutation {g,15-g,16+g,31-g} (34 tiles/CU) is now
// fully concurrent. Constant-shift softmax; lrow is ONE scalar per lane
// (q = col); output stores are b64.
// ---------------------------------------------------------------------------
__global__ __launch_bounds__(256, 4)
void flash_attn(const bf16* __restrict__ Q, const bf16* __restrict__ Kt,
                const bf16* __restrict__ VTg, bf16* __restrict__ O) {
  constexpr int QS = 2048;
  constexpr float SHIFT = 16.0f;
  __shared__ __attribute__((aligned(16))) bf16 K_lds[128 * 64];   // 16 KB
  __shared__ __attribute__((aligned(16))) bf16 VT_lds[64 * 128];  // 16 KB

  const int tid = threadIdx.x, wv = tid >> 6, lane = tid & 63;
  const int bh = blockIdx.x;            // 0..31  (XCD = bh % 8)
  const int y  = blockIdx.y;            // 0..31
  const int gq = y & 7, kq = y >> 3;
  const int qt = (kq == 0) ? gq : (kq == 1) ? (15 - gq)
               : (kq == 2) ? (16 + gq) : (31 - gq);
  const int b = bh >> 4, h = bh & 15;
  const int col = lane & 15, quad = lane >> 4;
  const size_t bS = (size_t)b * Sc;
  const int hd = h * 64;

  const int krow = tid >> 3;
  const int kcol = (((tid & 7) ^ (krow & 7)) << 3);
  const int vrow = tid >> 4;
  const int vcol = (((tid & 15) ^ vrow) << 3);
  const int cs8 = col & 7;

  // bpermute gather indices (bytes): lanes col+16*((2q)&3), col+16*((2q+1)&3)
  const int idxA = (col + 16 * ((2 * quad) & 3)) << 2;
  const int idxB = (col + 16 * ((2 * quad + 1) & 3)) << 2;

  const int qbase = qt * 64 + wv * 16;
  const int nkt = (qt + 2) >> 1;

  const bf16* qptr = Q + (bS + qbase + col) * QS + hd + quad * 8;
  bf16x8 qf[2];
  qf[0] = *(const bf16x8*)qptr;
  qf[1] = *(const bf16x8*)(qptr + 32);
#pragma unroll
  for (int hh = 0; hh < 2; hh++)
#pragma unroll
    for (int j = 0; j < 8; j++) qf[hh][j] = (bf16)((float)qf[hh][j] * 0.125f);

  f32x4 oacc[4];   // oacc[nb][r]: d = nb*16 + quad*4 + r, q = col
#pragma unroll
  for (int i = 0; i < 4; i++) oacc[i] = f32x4{0.f, 0.f, 0.f, 0.f};
  float lsum = 0.f;   // per-lane: full denominator for q = col (after reduce)

  for (int kt0 = 0; kt0 < nkt; kt0++) {
    const int k0 = kt0 * 128;
#pragma unroll
    for (int c = 0; c < 4; c++) {
      load_lds16(Kt + (bS + k0 + c * 32 + krow) * QS + hd + kcol,
                 K_lds + c * 2048 + tid * 8);
      load_lds16(VTg + ((size_t)bh * 64 + c * 16 + vrow) * 2048 + k0 + vcol,
                 VT_lds + c * 2048 + tid * 8);
    }
    __syncthreads();

    // ---- S^T = K·Q^T: sacc[sub] holds keys sub*16+quad*4+r, q=col ----
    f32x4 sacc[8];
#pragma unroll
    for (int sub = 0; sub < 8; sub++) {
      f32x4 a = f32x4{0.f, 0.f, 0.f, 0.f};
#pragma unroll
      for (int hh = 0; hh < 2; hh++) {
        const int so = (((hh * 4 + quad) ^ cs8) << 3);
        bf16x8 kf = *(const bf16x8*)(K_lds + (sub * 16 + col) * 64 + so);
        a = __builtin_amdgcn_mfma_f32_16x16x32_bf16(kf, qf[hh], a, 0, 0, 0);
      }
      sacc[sub] = a;
    }
    if (kt0 == nkt - 1) {  // causal: key > q -> -inf (exp -> 0)
      const int qq = qbase + col;
#pragma unroll
      for (int sub = 0; sub < 8; sub++)
#pragma unroll
        for (int r = 0; r < 4; r++) {
          const int key = k0 + sub * 16 + quad * 4 + r;
          if (key > qq) sacc[sub][r] = NEG_BIG;
        }
    }
    // constant-shift exp + per-lane denominator accumulation
#pragma unroll
    for (int sub = 0; sub < 8; sub++)
#pragma unroll
      for (int r = 0; r < 4; r++)
        sacc[sub][r] = exp2f(sacc[sub][r] * L2E - SHIFT);
#pragma unroll
    for (int sub = 0; sub < 8; sub++)
      lsum += (sacc[sub][0] + sacc[sub][1]) + (sacc[sub][2] + sacc[sub][3]);
    // pack P rows to bf16 pairs: pkl/pkh[sub] = keys quad*4+{0,1}/{2,3}
    int pkl[8], pkh[8];
#pragma unroll
    for (int sub = 0; sub < 8; sub++) {
      pkl[sub] = packbf(sacc[sub][0], sacc[sub][1]);
      pkh[sub] = packbf(sacc[sub][2], sacc[sub][3]);
    }
    // ---- PV: out^T += V^T · P^T, P^T B-frags via bpermute ----
#pragma unroll
    for (int c = 0; c < 4; c++) {
      const int sLo = 2 * c, sHi = 2 * c + 1;
      i32x4 w;
      {
        int aL = __builtin_amdgcn_ds_bpermute(idxA, pkl[sLo]);
        int aH = __builtin_amdgcn_ds_bpermute(idxA, pkl[sHi]);
        w[0] = (quad < 2) ? aL : aH;
      }
      {
        int aL = __builtin_amdgcn_ds_bpermute(idxA, pkh[sLo]);
        int aH = __builtin_amdgcn_ds_bpermute(idxA, pkh[sHi]);
        w[1] = (quad < 2) ? aL : aH;
      }
      {
        int aL = __builtin_amdgcn_ds_bpermute(idxB, pkl[sLo]);
        int aH = __builtin_amdgcn_ds_bpermute(idxB, pkl[sHi]);
        w[2] = (quad < 2) ? aL : aH;
      }
      {
        int aL = __builtin_amdgcn_ds_bpermute(idxB, pkh[sLo]);
        int aH = __builtin_amdgcn_ds_bpermute(idxB, pkh[sHi]);
        w[3] = (quad < 2) ? aL : aH;
      }
      union { i32x4 wi; bf16x8 v; } pb;
      pb.wi = w;
      const int vso = (((c * 4 + quad) ^ col) << 3);
#pragma unroll
      for (int nb = 0; nb < 4; nb++) {
        bf16x8 vf = *(const bf16x8*)(VT_lds + (nb * 16 + col) * 128 + vso);
        oacc[nb] = __builtin_amdgcn_mfma_f32_16x16x32_bf16(vf, pb.v, oacc[nb], 0, 0, 0);
      }
    }
    __syncthreads();
  }

  // reduce denominator across the 4 quads sharing col (2 shuffles)
  lsum += __shfl_xor(lsum, 16, 64);
  lsum += __shfl_xor(lsum, 32, 64);
  const float inv = 1.0f / fmaxf(lsum, 1e-37f);
  // store: out^T C-layout -> O[q][d], d = nb*16+quad*4+r contiguous (b64)
  const int qq = qbase + col;
#pragma unroll
  for (int nb = 0; nb < 4; nb++) {
    bf16x4 ov;
#pragma unroll
    for (int r = 0; r < 4; r++) ov[r] = (bf16)(oacc[nb][r] * inv);
    *(bf16x4*)(O + (bS + qq) * 1024 + hd + nb * 16 + quad * 4) = ov;
  }
}

// ---------------------------------------------------------------------------
extern "C" void kernel_launch(void* const* d_in, const int* in_sizes, int n_in,
                              void* d_out, int out_size, void* d_ws, size_t ws_size,
                              hipStream_t stream) {
  (void)in_sizes; (void)n_in; (void)out_size; (void)ws_size;
  const float* hs   = (const float*)d_in[0];
  const float* Wqkv = (const float*)d_in[1];
  const float* bqkv = (const float*)d_in[2];
  const float* Wqa  = (const float*)d_in[3];
  const float* bqa  = (const float*)d_in[4];
  const float* Wka  = (const float*)d_in[5];
  const float* bka  = (const float*)d_in[6];
  const float* Wd   = (const float*)d_in[7];
  const float* bd   = (const float*)d_in[8];
  float* out = (float*)d_out;

  const size_t TH = (size_t)Tc * Hc;            // 4,194,304
  bf16* dob   = (bf16*)d_out;
  bf16* hsb   = dob;
  bf16* wqkvb = dob + TH;
  bf16* Ah    = dob;
  bf16* VTg   = dob + TH;
  bf16* ws     = (bf16*)d_ws;
  bf16* qkv    = ws;
  bf16* qaka   = ws;
  bf16* oh     = ws + 2 * TH;
  bf16* wqakab = ws + 3 * TH;
  bf16* wdb    = wqakab + 2 * 1024 * 1024;
  float* bqaka = (float*)(wdb + 1024 * 1024);

  convert_all<<<dim3(5121), 256, 0, stream>>>(hs, Wqkv, Wqa, Wka, Wd, bqa, bka,
                                              hsb, wqkvb, wqakab, wdb, bqaka);

  gemm128<bf16><<<dim3(24, 32), 256, 0, stream>>>(hsb, wqkvb, bqkv, qkv, Tc, 3 * Hc, Hc);
  window_attn<<<dim3(Tc * NHc / 16), 256, 0, stream>>>(qkv, Ah, VTg);
  gemm128<bf16><<<dim3(16, 32), 256, 0, stream>>>(Ah, wqakab, bqaka, qaka, Tc, 2 * Hc, Hc);
  // flash: 1024 blocks, CU-balanced qt permutation, XCD = bh%8, 4 blocks/CU
  flash_attn<<<dim3(Bc * NHc, 32), 256, 0, stream>>>(qaka, qaka + Hc, VTg, oh);
  gemm6464<float><<<dim3(16, 64), 256, 0, stream>>>(oh, wdb, bd, out, Tc, Hc, Hc);
}